// Round 9
// baseline (398.278 us; speedup 1.0000x reference)
//
#include <hip/hip_runtime.h>

// ---------------- problem constants ----------------
static constexpr int N_NODES = 100000;
static constexpr int N_EDGES = 3200000;
static constexpr int SHIFT  = 8;                          // 256 nodes / bucket
static constexpr int NPB    = 1 << SHIFT;                 // 256
static constexpr int NBK    = (N_NODES + NPB - 1) / NPB;  // 391 buckets
static constexpr int WGC    = 2000;                       // partition workgroups
static constexpr int CHUNK  = N_EDGES / WGC;              // 1600 edges / WG (exact)
static constexpr int PSPLIT = 2;                          // WGs per bucket in reduce

// global record (uint4): .x = bf16 m0|m1, .y = bf16 m2|m3, .z = loc, .w = gslot

// ---------------- bf16 helpers ----------------
__device__ __forceinline__ unsigned bf16rne(float f) {
    unsigned u = __float_as_uint(f);
    u += 0x7fffu + ((u >> 16) & 1u);
    return u >> 16;
}
__device__ __forceinline__ unsigned pack2(float lo, float hi) {
    return bf16rne(lo) | (bf16rne(hi) << 16);
}

// ---- K1: per-WG histograms for both keys; transposed count matrices [NBK][WGC]
__global__ void __launch_bounds__(256) k_count(
    const int* __restrict__ row, const int* __restrict__ col,
    unsigned* __restrict__ cmC, unsigned* __restrict__ cmR)
{
    __shared__ unsigned hC[NBK], hR[NBK];
    for (int b = threadIdx.x; b < NBK; b += 256) { hC[b] = 0u; hR[b] = 0u; }
    __syncthreads();
    int w = blockIdx.x, e0 = w * CHUNK;
    for (int e = e0 + threadIdx.x; e < e0 + CHUNK; e += 256) {
        atomicAdd(&hC[col[e] >> SHIFT], 1u);
        atomicAdd(&hR[row[e] >> SHIFT], 1u);
    }
    __syncthreads();
    for (int b = threadIdx.x; b < NBK; b += 256) {
        cmC[(size_t)b * WGC + w] = hC[b];
        cmR[(size_t)b * WGC + w] = hR[b];
    }
}

// ---- K2: exclusive prefix over WGs per bucket (one warp per bucket row)
__global__ void __launch_bounds__(256) k_prefix(
    unsigned* __restrict__ cmC, unsigned* __restrict__ cmR,
    unsigned* __restrict__ totC, unsigned* __restrict__ totR)
{
    int warp = (blockIdx.x * 256 + threadIdx.x) >> 6;
    int lane = threadIdx.x & 63;
    if (warp >= 2 * NBK) return;
    unsigned* cm  = (warp < NBK) ? cmC : cmR;
    unsigned* tot = (warp < NBK) ? totC : totR;
    int b = (warp < NBK) ? warp : warp - NBK;
    unsigned* rowp = cm + (size_t)b * WGC;
    unsigned carry = 0;
    for (int base = 0; base < WGC; base += 64) {
        int idx = base + lane;
        unsigned v = (idx < WGC) ? rowp[idx] : 0u;
        unsigned inc = v;
        for (int off = 1; off < 64; off <<= 1) {
            unsigned t = __shfl_up(inc, off, 64);
            if (lane >= off) inc += t;
        }
        if (idx < WGC) rowp[idx] = carry + inc - v;   // exclusive
        carry += __shfl(inc, 63, 64);
    }
    if (lane == 0) tot[b] = carry;
}

// ---- K3: exclusive scan of bucket totals -> bucket bases (blockIdx 0: col, 1: row)
__global__ void __launch_bounds__(256) k_scan(
    const unsigned* __restrict__ totC, const unsigned* __restrict__ totR,
    unsigned* __restrict__ baseC, unsigned* __restrict__ baseR)
{
    const unsigned* tot = blockIdx.x ? totR : totC;
    unsigned* base = blockIdx.x ? baseR : baseC;
    __shared__ unsigned tsum[256];
    int tid = threadIdx.x;
    unsigned a0 = (2 * tid     < NBK) ? tot[2 * tid]     : 0u;
    unsigned a1 = (2 * tid + 1 < NBK) ? tot[2 * tid + 1] : 0u;
    tsum[tid] = a0 + a1;
    __syncthreads();
    for (int off = 1; off < 256; off <<= 1) {
        unsigned v = (tid >= off) ? tsum[tid - off] : 0u;
        __syncthreads();
        tsum[tid] += v;
        __syncthreads();
    }
    unsigned ex = tid ? tsum[tid - 1] : 0u;
    if (2 * tid     < NBK) base[2 * tid]     = ex;
    if (2 * tid + 1 < NBK) base[2 * tid + 1] = ex + a0;
}

// ---- K4: fused compute+partition. boo streamed COALESCED; bf16 message records
//      LDS-staged and written out in bucket-sorted coalesced runs. Global slot
//      computed at scatter time (no binary search).
template<int TRANS>
__global__ void __launch_bounds__(256) k_partmsg(
    const int* __restrict__ key,       // destination index (col p1 / row p2)
    const int* __restrict__ pay,       // source index      (row p1 / col p2)
    const float4* __restrict__ vin,    // x (p1) or lt (p2) — L2-resident gather
    const float4* __restrict__ boo,
    const unsigned* __restrict__ cm,   // prefix'd count matrix [NBK][WGC]
    const unsigned* __restrict__ base, // bucket bases [NBK]
    uint4* __restrict__ msgbuf)
{
    __shared__ uint4 stage[CHUNK];          // 25.6 KB
    __shared__ unsigned hist[NBK];          // counts -> cursors
    __shared__ unsigned runstart[NBK + 1];
    __shared__ unsigned gdst[NBK];
    __shared__ unsigned tsum[256];
    int w = blockIdx.x, tid = threadIdx.x, e0 = w * CHUNK;

    for (int b = tid; b < NBK; b += 256) {
        hist[b] = 0u;
        gdst[b] = base[b] + cm[(size_t)b * WGC + w];
    }
    __syncthreads();
    for (int e = e0 + tid; e < e0 + CHUNK; e += 256)
        atomicAdd(&hist[key[e] >> SHIFT], 1u);
    __syncthreads();
    // block exclusive scan of hist -> runstart
    unsigned a0 = (2 * tid     < NBK) ? hist[2 * tid]     : 0u;
    unsigned a1 = (2 * tid + 1 < NBK) ? hist[2 * tid + 1] : 0u;
    tsum[tid] = a0 + a1;
    __syncthreads();
    for (int off = 1; off < 256; off <<= 1) {
        unsigned v = (tid >= off) ? tsum[tid - off] : 0u;
        __syncthreads();
        tsum[tid] += v;
        __syncthreads();
    }
    unsigned ex = tid ? tsum[tid - 1] : 0u;
    if (2 * tid     <= NBK) runstart[2 * tid]     = ex;
    if (2 * tid + 1 <= NBK) runstart[2 * tid + 1] = ex + a0;
    __syncthreads();
    for (int b = tid; b < NBK; b += 256) hist[b] = runstart[b];  // cursors
    __syncthreads();

    // compute + stage (boo read is coalesced: consecutive threads, consecutive edges)
    for (int e = e0 + tid; e < e0 + CHUNK; e += 256) {
        int k = key[e];
        int p = pay[e];
        int b = k >> SHIFT;
        float4 v  = vin[p];
        float4 q0 = boo[(size_t)e * 4 + 0];
        float4 q1 = boo[(size_t)e * 4 + 1];
        float4 q2 = boo[(size_t)e * 4 + 2];
        float4 q3 = boo[(size_t)e * 4 + 3];
        float m0, m1, m2, m3;
        if (TRANS) {  // A^T v
            m0 = q0.x * v.x + q1.x * v.y + q2.x * v.z + q3.x * v.w;
            m1 = q0.y * v.x + q1.y * v.y + q2.y * v.z + q3.y * v.w;
            m2 = q0.z * v.x + q1.z * v.y + q2.z * v.z + q3.z * v.w;
            m3 = q0.w * v.x + q1.w * v.y + q2.w * v.z + q3.w * v.w;
        } else {      // A v
            m0 = q0.x * v.x + q0.y * v.y + q0.z * v.z + q0.w * v.w;
            m1 = q1.x * v.x + q1.y * v.y + q1.z * v.z + q1.w * v.w;
            m2 = q2.x * v.x + q2.y * v.y + q2.z * v.z + q2.w * v.w;
            m3 = q3.x * v.x + q3.y * v.y + q3.z * v.z + q3.w * v.w;
        }
        unsigned pos = atomicAdd(&hist[b], 1u);
        unsigned gs  = gdst[b] + (pos - runstart[b]);
        stage[pos] = make_uint4(pack2(m0, m1), pack2(m2, m3),
                                (unsigned)(k & (NPB - 1)), gs);
    }
    __syncthreads();

    // coalesced write-out: contiguous slots -> mostly-contiguous global runs
    for (int s = tid; s < CHUNK; s += 256) {
        uint4 r = stage[s];
        msgbuf[r.w] = r;
    }
}

// ---- K5: stream sorted records contiguously, f32 LDS accumulate,
//      merge partials via sector-merged global atomics (vout pre-zeroed).
__global__ void __launch_bounds__(512) k_reducemsg(
    const uint4* __restrict__ msgbuf,
    const unsigned* __restrict__ base, const unsigned* __restrict__ tot,
    float* __restrict__ vout)
{
    __shared__ float acc[NPB][4];
    int b = blockIdx.x / PSPLIT, sub = blockIdx.x % PSPLIT;
    int tid = threadIdx.x;
    for (int i = tid; i < NPB * 4; i += 512) ((float*)acc)[i] = 0.f;
    __syncthreads();
    unsigned start = base[b], n = tot[b];
    for (unsigned i = start + sub * 512 + tid; i < start + n; i += 512 * PSPLIT) {
        uint4 r = msgbuf[i];
        int loc = (int)r.z;
        atomicAdd(&acc[loc][0], __uint_as_float(r.x << 16));
        atomicAdd(&acc[loc][1], __uint_as_float(r.x & 0xffff0000u));
        atomicAdd(&acc[loc][2], __uint_as_float(r.y << 16));
        atomicAdd(&acc[loc][3], __uint_as_float(r.y & 0xffff0000u));
    }
    __syncthreads();
    for (int i = tid; i < NPB; i += 512) {
        int node = b * NPB + i;
        if (node < N_NODES) {
            float* dst = vout + (size_t)node * 4;
            atomicAdd(dst + 0, acc[i][0]);
            atomicAdd(dst + 1, acc[i][1]);
            atomicAdd(dst + 2, acc[i][2]);
            atomicAdd(dst + 3, acc[i][3]);
        }
    }
}

// ================= fallback path (R3: sector-merged global atomics) =================

__global__ void __launch_bounds__(256) llt_pass1(
    const float* __restrict__ x, const int* __restrict__ row_idx,
    const int* __restrict__ col_idx, const float* __restrict__ boo,
    float* __restrict__ lt)
{
    int t = blockIdx.x * blockDim.x + threadIdx.x;
    if (t >= N_EDGES * 4) return;
    int e = t >> 2, i = t & 3;
    int r = row_idx[e], c = col_idx[e];
    const float* A = boo + (size_t)e * 16;
    const float* xv = x + (size_t)r * 4;
    float m = A[0*4+i]*xv[0] + A[1*4+i]*xv[1] + A[2*4+i]*xv[2] + A[3*4+i]*xv[3];
    atomicAdd(lt + (size_t)c * 4 + i, m);
}

__global__ void __launch_bounds__(256) llt_pass2(
    const float4* __restrict__ lt, const int* __restrict__ row_idx,
    const int* __restrict__ col_idx, const float4* __restrict__ boo,
    float* __restrict__ out)
{
    int t = blockIdx.x * blockDim.x + threadIdx.x;
    if (t >= N_EDGES * 4) return;
    int e = t >> 2, i = t & 3;
    int r = row_idx[e], c = col_idx[e];
    float4 arow = boo[(size_t)e * 4 + i];
    float4 lv = lt[c];
    float m = arow.x*lv.x + arow.y*lv.y + arow.z*lv.z + arow.w*lv.w;
    atomicAdd(out + (size_t)r * 4 + i, m);
}

// ================= host =================

extern "C" void kernel_launch(void* const* d_in, const int* in_sizes, int n_in,
                              void* d_out, int out_size, void* d_ws, size_t ws_size,
                              hipStream_t stream) {
    const float4* x = (const float4*)d_in[0];        // [100000,4] f32
    const int* edge_index = (const int*)d_in[1];     // [2, 3200000] int32
    const float4* boo = (const float4*)d_in[2];      // [3200000,4,4] f32
    const int* row = edge_index;                     // edge_index[0]
    const int* col = edge_index + N_EDGES;           // edge_index[1]
    float* out = (float*)d_out;

    auto align256 = [](size_t v) { return (v + 255) & ~(size_t)255; };
    const size_t sz_cm  = align256((size_t)NBK * WGC * 4);   // ~3.13 MB each
    const size_t sz_vec = align256((size_t)NBK * 4);
    const size_t sz_msg = align256((size_t)N_EDGES * 16);    // 51.2 MB (reused)
    const size_t sz_lt  = align256((size_t)N_NODES * 16);    // 1.6 MB
    const size_t need = 2 * sz_cm + 4 * sz_vec + sz_msg + sz_lt;

    if (ws_size >= need) {
        char* p = (char*)d_ws;
        unsigned* cmC   = (unsigned*)p; p += sz_cm;
        unsigned* cmR   = (unsigned*)p; p += sz_cm;
        unsigned* totC  = (unsigned*)p; p += sz_vec;
        unsigned* totR  = (unsigned*)p; p += sz_vec;
        unsigned* baseC = (unsigned*)p; p += sz_vec;
        unsigned* baseR = (unsigned*)p; p += sz_vec;
        uint4*    msg   = (uint4*)p;    p += sz_msg;
        float*    lt    = (float*)p;    p += sz_lt;

        hipMemsetAsync(lt, 0, (size_t)N_NODES * 4 * sizeof(float), stream);
        hipMemsetAsync(out, 0, (size_t)N_NODES * 4 * sizeof(float), stream);

        k_count<<<WGC, 256, 0, stream>>>(row, col, cmC, cmR);
        k_prefix<<<(2 * NBK + 3) / 4, 256, 0, stream>>>(cmC, cmR, totC, totR);
        k_scan<<<2, 256, 0, stream>>>(totC, totR, baseC, baseR);
        // pass 1: bucket by col, message = A^T x[row] -> lt
        k_partmsg<1><<<WGC, 256, 0, stream>>>(col, row, x, boo, cmC, baseC, msg);
        k_reducemsg<<<NBK * PSPLIT, 512, 0, stream>>>(msg, baseC, totC, lt);
        // pass 2: bucket by row, message = A lt[col] -> out  (msg buffer reused)
        k_partmsg<0><<<WGC, 256, 0, stream>>>(row, col, (const float4*)lt, boo, cmR, baseR, msg);
        k_reducemsg<<<NBK * PSPLIT, 512, 0, stream>>>(msg, baseR, totR, out);
    } else {
        // fallback: sector-merged atomics (R3, 328 us)
        float* ltf = (float*)d_ws;
        hipMemsetAsync(ltf, 0, (size_t)N_NODES * 4 * sizeof(float), stream);
        hipMemsetAsync(out, 0, (size_t)N_NODES * 4 * sizeof(float), stream);
        const int grid = (N_EDGES * 4 + 255) / 256;
        llt_pass1<<<grid, 256, 0, stream>>>((const float*)x, row, col, (const float*)boo, ltf);
        llt_pass2<<<grid, 256, 0, stream>>>((const float4*)ltf, row, col, boo, out);
    }
}

// Round 10
// 391.743 us; speedup vs baseline: 1.0167x; 1.0167x over previous
//
#include <hip/hip_runtime.h>

// ---------------- problem constants ----------------
static constexpr int N_NODES = 100000;
static constexpr int N_EDGES = 3200000;
static constexpr int SHIFT  = 8;                          // 256 nodes / bucket
static constexpr int NPB    = 1 << SHIFT;                 // 256
static constexpr int NBK    = (N_NODES + NPB - 1) / NPB;  // 391 buckets
static constexpr int WGC    = 2000;                       // partition workgroups
static constexpr int CHUNK  = N_EDGES / WGC;              // 1600 edges / WG (exact)

// ---------------- bf16 helpers ----------------
__device__ __forceinline__ unsigned bf16rne(float f) {
    unsigned u = __float_as_uint(f);
    u += 0x7fffu + ((u >> 16) & 1u);
    return u >> 16;
}
__device__ __forceinline__ unsigned pack2(float lo, float hi) {
    return bf16rne(lo) | (bf16rne(hi) << 16);
}

// ---- K0: pure streaming compute. boo coalesced, vin gather (L2-resident),
//      8B bf16 message written in EDGE ORDER. No LDS, no barriers.
template<int TRANS>
__global__ void __launch_bounds__(256) k_msg(
    const int* __restrict__ pay,       // source index (row p1 / col p2)
    const float4* __restrict__ vin,    // x (p1) or lt (p2)
    const float4* __restrict__ boo,
    uint2* __restrict__ msgE)          // [N_EDGES] messages, edge order
{
    int e = blockIdx.x * 256 + threadIdx.x;
    if (e >= N_EDGES) return;
    float4 v  = vin[pay[e]];
    float4 q0 = boo[(size_t)e * 4 + 0];
    float4 q1 = boo[(size_t)e * 4 + 1];
    float4 q2 = boo[(size_t)e * 4 + 2];
    float4 q3 = boo[(size_t)e * 4 + 3];
    float m0, m1, m2, m3;
    if (TRANS) {  // A^T v
        m0 = q0.x * v.x + q1.x * v.y + q2.x * v.z + q3.x * v.w;
        m1 = q0.y * v.x + q1.y * v.y + q2.y * v.z + q3.y * v.w;
        m2 = q0.z * v.x + q1.z * v.y + q2.z * v.z + q3.z * v.w;
        m3 = q0.w * v.x + q1.w * v.y + q2.w * v.z + q3.w * v.w;
    } else {      // A v
        m0 = q0.x * v.x + q0.y * v.y + q0.z * v.z + q0.w * v.w;
        m1 = q1.x * v.x + q1.y * v.y + q1.z * v.z + q1.w * v.w;
        m2 = q2.x * v.x + q2.y * v.y + q2.z * v.z + q2.w * v.w;
        m3 = q3.x * v.x + q3.y * v.y + q3.z * v.z + q3.w * v.w;
    }
    msgE[e] = make_uint2(pack2(m0, m1), pack2(m2, m3));
}

// ---- K1: per-WG histograms for both keys; transposed count matrices [NBK][WGC]
__global__ void __launch_bounds__(256) k_count(
    const int* __restrict__ row, const int* __restrict__ col,
    unsigned* __restrict__ cmC, unsigned* __restrict__ cmR)
{
    __shared__ unsigned hC[NBK], hR[NBK];
    for (int b = threadIdx.x; b < NBK; b += 256) { hC[b] = 0u; hR[b] = 0u; }
    __syncthreads();
    int w = blockIdx.x, e0 = w * CHUNK;
    for (int e = e0 + threadIdx.x; e < e0 + CHUNK; e += 256) {
        atomicAdd(&hC[col[e] >> SHIFT], 1u);
        atomicAdd(&hR[row[e] >> SHIFT], 1u);
    }
    __syncthreads();
    for (int b = threadIdx.x; b < NBK; b += 256) {
        cmC[(size_t)b * WGC + w] = hC[b];
        cmR[(size_t)b * WGC + w] = hR[b];
    }
}

// ---- K2: exclusive prefix over WGs per bucket (one warp per bucket row)
__global__ void __launch_bounds__(256) k_prefix(
    unsigned* __restrict__ cmC, unsigned* __restrict__ cmR,
    unsigned* __restrict__ totC, unsigned* __restrict__ totR)
{
    int warp = (blockIdx.x * 256 + threadIdx.x) >> 6;
    int lane = threadIdx.x & 63;
    if (warp >= 2 * NBK) return;
    unsigned* cm  = (warp < NBK) ? cmC : cmR;
    unsigned* tot = (warp < NBK) ? totC : totR;
    int b = (warp < NBK) ? warp : warp - NBK;
    unsigned* rowp = cm + (size_t)b * WGC;
    unsigned carry = 0;
    for (int base = 0; base < WGC; base += 64) {
        int idx = base + lane;
        unsigned v = (idx < WGC) ? rowp[idx] : 0u;
        unsigned inc = v;
        for (int off = 1; off < 64; off <<= 1) {
            unsigned t = __shfl_up(inc, off, 64);
            if (lane >= off) inc += t;
        }
        if (idx < WGC) rowp[idx] = carry + inc - v;   // exclusive
        carry += __shfl(inc, 63, 64);
    }
    if (lane == 0) tot[b] = carry;
}

// ---- K3: exclusive scan of bucket totals -> bucket bases (blockIdx 0: col, 1: row)
__global__ void __launch_bounds__(256) k_scan(
    const unsigned* __restrict__ totC, const unsigned* __restrict__ totR,
    unsigned* __restrict__ baseC, unsigned* __restrict__ baseR)
{
    const unsigned* tot = blockIdx.x ? totR : totC;
    unsigned* base = blockIdx.x ? baseR : baseC;
    __shared__ unsigned tsum[256];
    int tid = threadIdx.x;
    unsigned a0 = (2 * tid     < NBK) ? tot[2 * tid]     : 0u;
    unsigned a1 = (2 * tid + 1 < NBK) ? tot[2 * tid + 1] : 0u;
    tsum[tid] = a0 + a1;
    __syncthreads();
    for (int off = 1; off < 256; off <<= 1) {
        unsigned v = (tid >= off) ? tsum[tid - off] : 0u;
        __syncthreads();
        tsum[tid] += v;
        __syncthreads();
    }
    unsigned ex = tid ? tsum[tid - 1] : 0u;
    if (2 * tid     < NBK) base[2 * tid]     = ex;
    if (2 * tid + 1 < NBK) base[2 * tid + 1] = ex + a0;
}

// ---- K4: partition precomputed messages into bucket-sorted split streams.
//      LDS-staged, slot computed at scatter (no binary search).
__global__ void __launch_bounds__(256) k_part(
    const int* __restrict__ key,       // destination index (col p1 / row p2)
    const uint2* __restrict__ msgE,    // messages in edge order
    const unsigned* __restrict__ cm,   // prefix'd count matrix [NBK][WGC]
    const unsigned* __restrict__ base, // bucket bases [NBK]
    uint2* __restrict__ msgS,          // sorted messages
    unsigned char* __restrict__ locS)  // sorted local node ids
{
    __shared__ uint4 stage[CHUNK];          // 25.6 KB
    __shared__ unsigned hist[NBK];
    __shared__ unsigned runstart[NBK + 1];
    __shared__ unsigned gdst[NBK];
    __shared__ unsigned tsum[256];
    int w = blockIdx.x, tid = threadIdx.x, e0 = w * CHUNK;

    for (int b = tid; b < NBK; b += 256) {
        hist[b] = 0u;
        gdst[b] = base[b] + cm[(size_t)b * WGC + w];
    }
    __syncthreads();
    for (int e = e0 + tid; e < e0 + CHUNK; e += 256)
        atomicAdd(&hist[key[e] >> SHIFT], 1u);
    __syncthreads();
    unsigned a0 = (2 * tid     < NBK) ? hist[2 * tid]     : 0u;
    unsigned a1 = (2 * tid + 1 < NBK) ? hist[2 * tid + 1] : 0u;
    tsum[tid] = a0 + a1;
    __syncthreads();
    for (int off = 1; off < 256; off <<= 1) {
        unsigned v = (tid >= off) ? tsum[tid - off] : 0u;
        __syncthreads();
        tsum[tid] += v;
        __syncthreads();
    }
    unsigned ex = tid ? tsum[tid - 1] : 0u;
    if (2 * tid     <= NBK) runstart[2 * tid]     = ex;
    if (2 * tid + 1 <= NBK) runstart[2 * tid + 1] = ex + a0;
    __syncthreads();
    for (int b = tid; b < NBK; b += 256) hist[b] = runstart[b];  // cursors
    __syncthreads();

    for (int e = e0 + tid; e < e0 + CHUNK; e += 256) {
        int k = key[e];
        uint2 m = msgE[e];
        int b = k >> SHIFT;
        unsigned pos = atomicAdd(&hist[b], 1u);
        unsigned gs  = gdst[b] + (pos - runstart[b]);
        stage[pos] = make_uint4(m.x, m.y, (unsigned)(k & (NPB - 1)), gs);
    }
    __syncthreads();

    // write-out: slots contiguous -> bucket runs mostly coalesced
    for (int s = tid; s < CHUNK; s += 256) {
        uint4 r = stage[s];
        msgS[r.w] = make_uint2(r.x, r.y);
        locS[r.w] = (unsigned char)r.z;
    }
}

// ---- K5: one WG per bucket: stream sorted records contiguously, f32 LDS
//      accumulate, direct store. No pre-zero needed.
__global__ void __launch_bounds__(1024) k_reduce(
    const uint2* __restrict__ msgS, const unsigned char* __restrict__ locS,
    const unsigned* __restrict__ base, const unsigned* __restrict__ tot,
    float4* __restrict__ vout)
{
    __shared__ float acc[NPB][4];
    int b = blockIdx.x, tid = threadIdx.x;
    if (tid < NPB * 4) ((float*)acc)[tid] = 0.f;
    __syncthreads();
    unsigned start = base[b], n = tot[b];
    for (unsigned i = start + tid; i < start + n; i += 1024) {
        uint2 m = msgS[i];
        int loc = locS[i];
        atomicAdd(&acc[loc][0], __uint_as_float(m.x << 16));
        atomicAdd(&acc[loc][1], __uint_as_float(m.x & 0xffff0000u));
        atomicAdd(&acc[loc][2], __uint_as_float(m.y << 16));
        atomicAdd(&acc[loc][3], __uint_as_float(m.y & 0xffff0000u));
    }
    __syncthreads();
    if (tid < NPB) {
        int node = b * NPB + tid;
        if (node < N_NODES)
            vout[node] = make_float4(acc[tid][0], acc[tid][1],
                                     acc[tid][2], acc[tid][3]);
    }
}

// ================= fallback path (R3: sector-merged global atomics) =================

__global__ void __launch_bounds__(256) llt_pass1(
    const float* __restrict__ x, const int* __restrict__ row_idx,
    const int* __restrict__ col_idx, const float* __restrict__ boo,
    float* __restrict__ lt)
{
    int t = blockIdx.x * blockDim.x + threadIdx.x;
    if (t >= N_EDGES * 4) return;
    int e = t >> 2, i = t & 3;
    int r = row_idx[e], c = col_idx[e];
    const float* A = boo + (size_t)e * 16;
    const float* xv = x + (size_t)r * 4;
    float m = A[0*4+i]*xv[0] + A[1*4+i]*xv[1] + A[2*4+i]*xv[2] + A[3*4+i]*xv[3];
    atomicAdd(lt + (size_t)c * 4 + i, m);
}

__global__ void __launch_bounds__(256) llt_pass2(
    const float4* __restrict__ lt, const int* __restrict__ row_idx,
    const int* __restrict__ col_idx, const float4* __restrict__ boo,
    float* __restrict__ out)
{
    int t = blockIdx.x * blockDim.x + threadIdx.x;
    if (t >= N_EDGES * 4) return;
    int e = t >> 2, i = t & 3;
    int r = row_idx[e], c = col_idx[e];
    float4 arow = boo[(size_t)e * 4 + i];
    float4 lv = lt[c];
    float m = arow.x*lv.x + arow.y*lv.y + arow.z*lv.z + arow.w*lv.w;
    atomicAdd(out + (size_t)r * 4 + i, m);
}

// ================= host =================

extern "C" void kernel_launch(void* const* d_in, const int* in_sizes, int n_in,
                              void* d_out, int out_size, void* d_ws, size_t ws_size,
                              hipStream_t stream) {
    const float4* x = (const float4*)d_in[0];        // [100000,4] f32
    const int* edge_index = (const int*)d_in[1];     // [2, 3200000] int32
    const float4* boo = (const float4*)d_in[2];      // [3200000,4,4] f32
    const int* row = edge_index;                     // edge_index[0]
    const int* col = edge_index + N_EDGES;           // edge_index[1]
    float4* out = (float4*)d_out;

    auto align256 = [](size_t v) { return (v + 255) & ~(size_t)255; };
    const size_t sz_cm   = align256((size_t)NBK * WGC * 4);   // 3.13 MB each
    const size_t sz_vec  = align256((size_t)NBK * 4);
    const size_t sz_msgE = align256((size_t)N_EDGES * 8);     // 25.6 MB
    const size_t sz_msgS = align256((size_t)N_EDGES * 8);     // 25.6 MB
    const size_t sz_loc  = align256((size_t)N_EDGES);         // 3.2 MB
    const size_t sz_lt   = align256((size_t)N_NODES * 16);    // 1.6 MB
    const size_t need = 2 * sz_cm + 4 * sz_vec + sz_msgE + sz_msgS + sz_loc + sz_lt;

    if (ws_size >= need) {
        char* p = (char*)d_ws;
        unsigned* cmC   = (unsigned*)p; p += sz_cm;
        unsigned* cmR   = (unsigned*)p; p += sz_cm;
        unsigned* totC  = (unsigned*)p; p += sz_vec;
        unsigned* totR  = (unsigned*)p; p += sz_vec;
        unsigned* baseC = (unsigned*)p; p += sz_vec;
        unsigned* baseR = (unsigned*)p; p += sz_vec;
        uint2*    msgE  = (uint2*)p;    p += sz_msgE;
        uint2*    msgS  = (uint2*)p;    p += sz_msgS;
        unsigned char* locS = (unsigned char*)p; p += sz_loc;
        float4*   lt    = (float4*)p;   p += sz_lt;

        const int mgrid = (N_EDGES + 255) / 256;

        k_count<<<WGC, 256, 0, stream>>>(row, col, cmC, cmR);
        k_prefix<<<(2 * NBK + 3) / 4, 256, 0, stream>>>(cmC, cmR, totC, totR);
        k_scan<<<2, 256, 0, stream>>>(totC, totR, baseC, baseR);
        // pass 1: msg = A^T x[row], bucket by col -> lt
        k_msg<1><<<mgrid, 256, 0, stream>>>(row, x, boo, msgE);
        k_part<<<WGC, 256, 0, stream>>>(col, msgE, cmC, baseC, msgS, locS);
        k_reduce<<<NBK, 1024, 0, stream>>>(msgS, locS, baseC, totC, lt);
        // pass 2: msg = A lt[col], bucket by row -> out
        k_msg<0><<<mgrid, 256, 0, stream>>>(col, (const float4*)lt, boo, msgE);
        k_part<<<WGC, 256, 0, stream>>>(row, msgE, cmR, baseR, msgS, locS);
        k_reduce<<<NBK, 1024, 0, stream>>>(msgS, locS, baseR, totR, out);
    } else {
        // fallback: sector-merged atomics (R3, 328 us)
        float* ltf = (float*)d_ws;
        hipMemsetAsync(ltf, 0, (size_t)N_NODES * 4 * sizeof(float), stream);
        hipMemsetAsync(out, 0, (size_t)N_NODES * 4 * sizeof(float), stream);
        const int grid = (N_EDGES * 4 + 255) / 256;
        llt_pass1<<<grid, 256, 0, stream>>>((const float*)x, row, col, (const float*)boo, ltf);
        llt_pass2<<<grid, 256, 0, stream>>>((const float4*)ltf, row, col, boo, (float*)out);
    }
}

// Round 11
// 382.571 us; speedup vs baseline: 1.0411x; 1.0240x over previous
//
#include <hip/hip_runtime.h>

// ---------------- problem constants ----------------
static constexpr int N_NODES = 100000;
static constexpr int N_EDGES = 3200000;
static constexpr int SHIFT  = 9;                          // 512 nodes / bucket
static constexpr int NPB    = 1 << SHIFT;                 // 512
static constexpr int NBK    = (N_NODES + NPB - 1) / NPB;  // 196 buckets
static constexpr int SLOTS  = NBK * NPB;                  // 100352
static constexpr int WGC    = 2000;                       // partition workgroups
static constexpr int CHUNK  = N_EDGES / WGC;              // 1600 edges / WG (exact)
static constexpr int PSPLIT = 8;                          // WGs per bucket in reduce

// ---------------- bf16 helpers ----------------
__device__ __forceinline__ unsigned bf16rne(float f) {
    unsigned u = __float_as_uint(f);
    u += 0x7fffu + ((u >> 16) & 1u);
    return u >> 16;
}

// ---- K0: streaming compute with DENSE boo reads. Thread t loads float4 #t
//      (16B lane stride -> 16 lines/instruction). 4-lane group = one edge
//      (lane q holds row q of A). Message via group shuffles; 2B bf16 store.
template<int TRANS>
__global__ void __launch_bounds__(256) k_msg(
    const int* __restrict__ pay,       // source index (row p1 / col p2)
    const float4* __restrict__ vin,    // x (p1) or lt (p2) — L2-resident gather
    const float4* __restrict__ boo4,   // boo as flat float4[N_EDGES*4]
    unsigned short* __restrict__ msgH) // [N_EDGES*4] bf16 messages, edge order
{
    int t = blockIdx.x * 256 + threadIdx.x;     // 0 .. N_EDGES*4
    int g = t >> 2;                             // edge id
    int q = t & 3;                              // row index within edge
    if (g >= N_EDGES) return;
    float4 rq = boo4[t];                        // DENSE coalesced
    float4 v  = vin[pay[g]];                    // 4 lanes share one line
    float mq;
    if (TRANS) {
        // m[i] = sum_q v[q]*A[q][i]; lane q contributes v[q]*row_q, group-sum
        float vq = (q == 0) ? v.x : (q == 1) ? v.y : (q == 2) ? v.z : v.w;
        float p0 = vq * rq.x, p1 = vq * rq.y, p2 = vq * rq.z, p3 = vq * rq.w;
        p0 += __shfl_xor(p0, 1, 64); p1 += __shfl_xor(p1, 1, 64);
        p2 += __shfl_xor(p2, 1, 64); p3 += __shfl_xor(p3, 1, 64);
        p0 += __shfl_xor(p0, 2, 64); p1 += __shfl_xor(p1, 2, 64);
        p2 += __shfl_xor(p2, 2, 64); p3 += __shfl_xor(p3, 2, 64);
        mq = (q == 0) ? p0 : (q == 1) ? p1 : (q == 2) ? p2 : p3;
    } else {
        // m[q] = dot(row_q, v)
        mq = rq.x * v.x + rq.y * v.y + rq.z * v.z + rq.w * v.w;
    }
    msgH[t] = (unsigned short)bf16rne(mq);      // 2B dense store
}

// ---- K1: per-WG histograms for both keys; transposed count matrices [NBK][WGC]
__global__ void __launch_bounds__(256) k_count(
    const int* __restrict__ row, const int* __restrict__ col,
    unsigned* __restrict__ cmC, unsigned* __restrict__ cmR)
{
    __shared__ unsigned hC[NBK], hR[NBK];
    for (int b = threadIdx.x; b < NBK; b += 256) { hC[b] = 0u; hR[b] = 0u; }
    __syncthreads();
    int w = blockIdx.x, e0 = w * CHUNK;
    for (int e = e0 + threadIdx.x; e < e0 + CHUNK; e += 256) {
        atomicAdd(&hC[col[e] >> SHIFT], 1u);
        atomicAdd(&hR[row[e] >> SHIFT], 1u);
    }
    __syncthreads();
    for (int b = threadIdx.x; b < NBK; b += 256) {
        cmC[(size_t)b * WGC + w] = hC[b];
        cmR[(size_t)b * WGC + w] = hR[b];
    }
}

// ---- K2: exclusive prefix over WGs per bucket (one warp per bucket row)
__global__ void __launch_bounds__(256) k_prefix(
    unsigned* __restrict__ cmC, unsigned* __restrict__ cmR,
    unsigned* __restrict__ totC, unsigned* __restrict__ totR)
{
    int warp = (blockIdx.x * 256 + threadIdx.x) >> 6;
    int lane = threadIdx.x & 63;
    if (warp >= 2 * NBK) return;
    unsigned* cm  = (warp < NBK) ? cmC : cmR;
    unsigned* tot = (warp < NBK) ? totC : totR;
    int b = (warp < NBK) ? warp : warp - NBK;
    unsigned* rowp = cm + (size_t)b * WGC;
    unsigned carry = 0;
    for (int base = 0; base < WGC; base += 64) {
        int idx = base + lane;
        unsigned v = (idx < WGC) ? rowp[idx] : 0u;
        unsigned inc = v;
        for (int off = 1; off < 64; off <<= 1) {
            unsigned t = __shfl_up(inc, off, 64);
            if (lane >= off) inc += t;
        }
        if (idx < WGC) rowp[idx] = carry + inc - v;   // exclusive
        carry += __shfl(inc, 63, 64);
    }
    if (lane == 0) tot[b] = carry;
}

// ---- K3: exclusive scan of bucket totals -> bucket bases (blockIdx 0: col, 1: row)
__global__ void __launch_bounds__(256) k_scan(
    const unsigned* __restrict__ totC, const unsigned* __restrict__ totR,
    unsigned* __restrict__ baseC, unsigned* __restrict__ baseR)
{
    const unsigned* tot = blockIdx.x ? totR : totC;
    unsigned* base = blockIdx.x ? baseR : baseC;
    __shared__ unsigned tsum[256];
    int tid = threadIdx.x;
    unsigned a0 = (2 * tid     < NBK) ? tot[2 * tid]     : 0u;
    unsigned a1 = (2 * tid + 1 < NBK) ? tot[2 * tid + 1] : 0u;
    tsum[tid] = a0 + a1;
    __syncthreads();
    for (int off = 1; off < 256; off <<= 1) {
        unsigned v = (tid >= off) ? tsum[tid - off] : 0u;
        __syncthreads();
        tsum[tid] += v;
        __syncthreads();
    }
    unsigned ex = tid ? tsum[tid - 1] : 0u;
    if (2 * tid     < NBK) base[2 * tid]     = ex;
    if (2 * tid + 1 < NBK) base[2 * tid + 1] = ex + a0;
}

// ---- K4: partition messages into bucket-sorted split streams. LDS-staged,
//      global slot computed at scatter time (no binary search).
__global__ void __launch_bounds__(256) k_part(
    const int* __restrict__ key,       // destination index (col p1 / row p2)
    const uint2* __restrict__ msgE,    // messages in edge order (4x bf16)
    const unsigned* __restrict__ cm,   // prefix'd count matrix [NBK][WGC]
    const unsigned* __restrict__ base, // bucket bases [NBK]
    uint2* __restrict__ msgS,          // sorted messages
    unsigned short* __restrict__ locS) // sorted local node ids (9 bits)
{
    __shared__ uint4 stage[CHUNK];          // 25.6 KB
    __shared__ unsigned hist[NBK];
    __shared__ unsigned runstart[NBK + 1];
    __shared__ unsigned gdst[NBK];
    __shared__ unsigned tsum[256];
    int w = blockIdx.x, tid = threadIdx.x, e0 = w * CHUNK;

    for (int b = tid; b < NBK; b += 256) {
        hist[b] = 0u;
        gdst[b] = base[b] + cm[(size_t)b * WGC + w];
    }
    __syncthreads();
    for (int e = e0 + tid; e < e0 + CHUNK; e += 256)
        atomicAdd(&hist[key[e] >> SHIFT], 1u);
    __syncthreads();
    unsigned a0 = (2 * tid     < NBK) ? hist[2 * tid]     : 0u;
    unsigned a1 = (2 * tid + 1 < NBK) ? hist[2 * tid + 1] : 0u;
    tsum[tid] = a0 + a1;
    __syncthreads();
    for (int off = 1; off < 256; off <<= 1) {
        unsigned v = (tid >= off) ? tsum[tid - off] : 0u;
        __syncthreads();
        tsum[tid] += v;
        __syncthreads();
    }
    unsigned ex = tid ? tsum[tid - 1] : 0u;
    if (2 * tid     <= NBK) runstart[2 * tid]     = ex;
    if (2 * tid + 1 <= NBK) runstart[2 * tid + 1] = ex + a0;
    __syncthreads();
    for (int b = tid; b < NBK; b += 256) hist[b] = runstart[b];  // cursors
    __syncthreads();

    for (int e = e0 + tid; e < e0 + CHUNK; e += 256) {
        int k = key[e];
        uint2 m = msgE[e];
        int b = k >> SHIFT;
        unsigned pos = atomicAdd(&hist[b], 1u);
        unsigned gs  = gdst[b] + (pos - runstart[b]);
        stage[pos] = make_uint4(m.x, m.y, (unsigned)(k & (NPB - 1)), gs);
    }
    __syncthreads();

    for (int s = tid; s < CHUNK; s += 256) {
        uint4 r = stage[s];
        msgS[r.w] = make_uint2(r.x, r.y);
        locS[r.w] = (unsigned short)r.z;
    }
}

// ---- K5: PSPLIT WGs per bucket: contiguous record stream, f32 LDS accumulate,
//      partials to per-sub buffer (no pre-zero, no global atomics).
__global__ void __launch_bounds__(512) k_reduce(
    const uint2* __restrict__ msgS, const unsigned short* __restrict__ locS,
    const unsigned* __restrict__ base, const unsigned* __restrict__ tot,
    float4* __restrict__ part)          // [PSPLIT][SLOTS]
{
    __shared__ float acc[4][NPB];       // planar: bank = loc%32
    int b = blockIdx.x / PSPLIT, sub = blockIdx.x % PSPLIT;
    int tid = threadIdx.x;
    for (int i = tid; i < 4 * NPB; i += 512) ((float*)acc)[i] = 0.f;
    __syncthreads();
    unsigned start = base[b], n = tot[b];
    for (unsigned i = start + sub * 512 + tid; i < start + n; i += 512 * PSPLIT) {
        uint2 m = msgS[i];
        int loc = locS[i];
        atomicAdd(&acc[0][loc], __uint_as_float(m.x << 16));
        atomicAdd(&acc[1][loc], __uint_as_float(m.x & 0xffff0000u));
        atomicAdd(&acc[2][loc], __uint_as_float(m.y << 16));
        atomicAdd(&acc[3][loc], __uint_as_float(m.y & 0xffff0000u));
    }
    __syncthreads();
    for (int i = tid; i < NPB; i += 512)
        part[(size_t)sub * SLOTS + (size_t)b * NPB + i] =
            make_float4(acc[0][i], acc[1][i], acc[2][i], acc[3][i]);
}

// ---- K6: merge PSPLIT partial buffers -> final vector
__global__ void __launch_bounds__(256) k_merge(
    const float4* __restrict__ part, float4* __restrict__ vout)
{
    int s = blockIdx.x * 256 + threadIdx.x;
    if (s >= N_NODES) return;
    float4 r = part[s];
    for (int sub = 1; sub < PSPLIT; ++sub) {
        float4 t = part[(size_t)sub * SLOTS + s];
        r.x += t.x; r.y += t.y; r.z += t.z; r.w += t.w;
    }
    vout[s] = r;
}

// ================= fallback path (R3: sector-merged global atomics) =================

__global__ void __launch_bounds__(256) llt_pass1(
    const float* __restrict__ x, const int* __restrict__ row_idx,
    const int* __restrict__ col_idx, const float* __restrict__ boo,
    float* __restrict__ lt)
{
    int t = blockIdx.x * blockDim.x + threadIdx.x;
    if (t >= N_EDGES * 4) return;
    int e = t >> 2, i = t & 3;
    int r = row_idx[e], c = col_idx[e];
    const float* A = boo + (size_t)e * 16;
    const float* xv = x + (size_t)r * 4;
    float m = A[0*4+i]*xv[0] + A[1*4+i]*xv[1] + A[2*4+i]*xv[2] + A[3*4+i]*xv[3];
    atomicAdd(lt + (size_t)c * 4 + i, m);
}

__global__ void __launch_bounds__(256) llt_pass2(
    const float4* __restrict__ lt, const int* __restrict__ row_idx,
    const int* __restrict__ col_idx, const float4* __restrict__ boo,
    float* __restrict__ out)
{
    int t = blockIdx.x * blockDim.x + threadIdx.x;
    if (t >= N_EDGES * 4) return;
    int e = t >> 2, i = t & 3;
    int r = row_idx[e], c = col_idx[e];
    float4 arow = boo[(size_t)e * 4 + i];
    float4 lv = lt[c];
    float m = arow.x*lv.x + arow.y*lv.y + arow.z*lv.z + arow.w*lv.w;
    atomicAdd(out + (size_t)r * 4 + i, m);
}

// ================= host =================

extern "C" void kernel_launch(void* const* d_in, const int* in_sizes, int n_in,
                              void* d_out, int out_size, void* d_ws, size_t ws_size,
                              hipStream_t stream) {
    const float4* x = (const float4*)d_in[0];        // [100000,4] f32
    const int* edge_index = (const int*)d_in[1];     // [2, 3200000] int32
    const float4* boo = (const float4*)d_in[2];      // [3200000,4,4] f32
    const int* row = edge_index;                     // edge_index[0]
    const int* col = edge_index + N_EDGES;           // edge_index[1]
    float4* out = (float4*)d_out;

    auto align256 = [](size_t v) { return (v + 255) & ~(size_t)255; };
    const size_t sz_cm   = align256((size_t)NBK * WGC * 4);   // 1.57 MB each
    const size_t sz_vec  = align256((size_t)NBK * 4);
    const size_t sz_msgE = align256((size_t)N_EDGES * 8);     // 25.6 MB
    const size_t sz_msgS = align256((size_t)N_EDGES * 8);     // 25.6 MB
    const size_t sz_loc  = align256((size_t)N_EDGES * 2);     // 6.4 MB
    const size_t sz_lt   = align256((size_t)N_NODES * 16);    // 1.6 MB
    const size_t sz_part = align256((size_t)PSPLIT * SLOTS * 16); // 12.9 MB
    const size_t need = 2 * sz_cm + 4 * sz_vec + sz_msgE + sz_msgS + sz_loc
                      + sz_lt + sz_part;

    if (ws_size >= need) {
        char* p = (char*)d_ws;
        unsigned* cmC   = (unsigned*)p; p += sz_cm;
        unsigned* cmR   = (unsigned*)p; p += sz_cm;
        unsigned* totC  = (unsigned*)p; p += sz_vec;
        unsigned* totR  = (unsigned*)p; p += sz_vec;
        unsigned* baseC = (unsigned*)p; p += sz_vec;
        unsigned* baseR = (unsigned*)p; p += sz_vec;
        unsigned short* msgH = (unsigned short*)p;   // view of msgE
        uint2*    msgE  = (uint2*)p;    p += sz_msgE;
        uint2*    msgS  = (uint2*)p;    p += sz_msgS;
        unsigned short* locS = (unsigned short*)p; p += sz_loc;
        float4*   lt    = (float4*)p;   p += sz_lt;
        float4*   part  = (float4*)p;   p += sz_part;

        const int mgrid = (N_EDGES * 4 + 255) / 256;  // 4 lanes per edge

        k_count<<<WGC, 256, 0, stream>>>(row, col, cmC, cmR);
        k_prefix<<<(2 * NBK + 3) / 4, 256, 0, stream>>>(cmC, cmR, totC, totR);
        k_scan<<<2, 256, 0, stream>>>(totC, totR, baseC, baseR);
        // pass 1: msg = A^T x[row], bucket by col -> lt
        k_msg<1><<<mgrid, 256, 0, stream>>>(row, x, boo, msgH);
        k_part<<<WGC, 256, 0, stream>>>(col, msgE, cmC, baseC, msgS, locS);
        k_reduce<<<NBK * PSPLIT, 512, 0, stream>>>(msgS, locS, baseC, totC, part);
        k_merge<<<(N_NODES + 255) / 256, 256, 0, stream>>>(part, lt);
        // pass 2: msg = A lt[col], bucket by row -> out
        k_msg<0><<<mgrid, 256, 0, stream>>>(col, (const float4*)lt, boo, msgH);
        k_part<<<WGC, 256, 0, stream>>>(row, msgE, cmR, baseR, msgS, locS);
        k_reduce<<<NBK * PSPLIT, 512, 0, stream>>>(msgS, locS, baseR, totR, part);
        k_merge<<<(N_NODES + 255) / 256, 256, 0, stream>>>(part, out);
    } else {
        // fallback: sector-merged atomics (R3, 328 us)
        float* ltf = (float*)d_ws;
        hipMemsetAsync(ltf, 0, (size_t)N_NODES * 4 * sizeof(float), stream);
        hipMemsetAsync(out, 0, (size_t)N_NODES * 4 * sizeof(float), stream);
        const int grid = (N_EDGES * 4 + 255) / 256;
        llt_pass1<<<grid, 256, 0, stream>>>((const float*)x, row, col, (const float*)boo, ltf);
        llt_pass2<<<grid, 256, 0, stream>>>((const float4*)ltf, row, col, boo, (float*)out);
    }
}

// Round 12
// 370.606 us; speedup vs baseline: 1.0747x; 1.0323x over previous
//
#include <hip/hip_runtime.h>

// ---------------- problem constants ----------------
static constexpr int N_NODES = 100000;
static constexpr int N_EDGES = 3200000;
static constexpr int SHIFT  = 10;                         // 1024 nodes / bucket
static constexpr int NPB    = 1 << SHIFT;                 // 1024
static constexpr int NBK    = (N_NODES + NPB - 1) / NPB;  // 98 buckets
static constexpr int SLOTS  = NBK * NPB;                  // 100352
static constexpr int WGC    = 1000;                       // partition workgroups
static constexpr int CHUNK  = N_EDGES / WGC;              // 3200 edges / WG (exact)
static constexpr int PSPLIT = 8;                          // WGs per bucket in reduce

// ---------------- bf16 helpers ----------------
__device__ __forceinline__ unsigned bf16rne(float f) {
    unsigned u = __float_as_uint(f);
    u += 0x7fffu + ((u >> 16) & 1u);
    return u >> 16;
}

// ---- K0: streaming compute, dense boo reads (thread t = float4 #t).
//      4-lane group = one edge; message via group shuffles (pass1) or direct dot.
template<int TRANS>
__global__ void __launch_bounds__(256) k_msg(
    const int* __restrict__ pay,
    const float4* __restrict__ vin,
    const float4* __restrict__ boo4,
    unsigned short* __restrict__ msgH)
{
    int t = blockIdx.x * 256 + threadIdx.x;
    int g = t >> 2;
    int q = t & 3;
    if (g >= N_EDGES) return;
    float4 rq = boo4[t];
    float4 v  = vin[pay[g]];
    float mq;
    if (TRANS) {
        float vq = (q == 0) ? v.x : (q == 1) ? v.y : (q == 2) ? v.z : v.w;
        float p0 = vq * rq.x, p1 = vq * rq.y, p2 = vq * rq.z, p3 = vq * rq.w;
        p0 += __shfl_xor(p0, 1, 64); p1 += __shfl_xor(p1, 1, 64);
        p2 += __shfl_xor(p2, 1, 64); p3 += __shfl_xor(p3, 1, 64);
        p0 += __shfl_xor(p0, 2, 64); p1 += __shfl_xor(p1, 2, 64);
        p2 += __shfl_xor(p2, 2, 64); p3 += __shfl_xor(p3, 2, 64);
        mq = (q == 0) ? p0 : (q == 1) ? p1 : (q == 2) ? p2 : p3;
    } else {
        mq = rq.x * v.x + rq.y * v.y + rq.z * v.z + rq.w * v.w;
    }
    msgH[t] = (unsigned short)bf16rne(mq);
}

// ---- K1: per-WG histograms (2 LDS replicas to halve same-address contention)
__global__ void __launch_bounds__(256) k_count(
    const int* __restrict__ row, const int* __restrict__ col,
    unsigned* __restrict__ cmC, unsigned* __restrict__ cmR)
{
    __shared__ unsigned hC[2][NBK], hR[2][NBK];
    for (int b = threadIdx.x; b < 2 * NBK; b += 256)
        { ((unsigned*)hC)[b] = 0u; ((unsigned*)hR)[b] = 0u; }
    __syncthreads();
    int w = blockIdx.x, e0 = w * CHUNK, rep = threadIdx.x & 1;
    for (int e = e0 + threadIdx.x; e < e0 + CHUNK; e += 256) {
        atomicAdd(&hC[rep][col[e] >> SHIFT], 1u);
        atomicAdd(&hR[rep][row[e] >> SHIFT], 1u);
    }
    __syncthreads();
    for (int b = threadIdx.x; b < NBK; b += 256) {
        cmC[(size_t)b * WGC + w] = hC[0][b] + hC[1][b];
        cmR[(size_t)b * WGC + w] = hR[0][b] + hR[1][b];
    }
}

// ---- K2: exclusive prefix over WGs per bucket (one warp per bucket row)
__global__ void __launch_bounds__(256) k_prefix(
    unsigned* __restrict__ cmC, unsigned* __restrict__ cmR,
    unsigned* __restrict__ totC, unsigned* __restrict__ totR)
{
    int warp = (blockIdx.x * 256 + threadIdx.x) >> 6;
    int lane = threadIdx.x & 63;
    if (warp >= 2 * NBK) return;
    unsigned* cm  = (warp < NBK) ? cmC : cmR;
    unsigned* tot = (warp < NBK) ? totC : totR;
    int b = (warp < NBK) ? warp : warp - NBK;
    unsigned* rowp = cm + (size_t)b * WGC;
    unsigned carry = 0;
    for (int base = 0; base < WGC; base += 64) {
        int idx = base + lane;
        unsigned v = (idx < WGC) ? rowp[idx] : 0u;
        unsigned inc = v;
        for (int off = 1; off < 64; off <<= 1) {
            unsigned t = __shfl_up(inc, off, 64);
            if (lane >= off) inc += t;
        }
        if (idx < WGC) rowp[idx] = carry + inc - v;
        carry += __shfl(inc, 63, 64);
    }
    if (lane == 0) tot[b] = carry;
}

// ---- K3: exclusive scan of bucket totals -> bucket bases
__global__ void __launch_bounds__(256) k_scan(
    const unsigned* __restrict__ totC, const unsigned* __restrict__ totR,
    unsigned* __restrict__ baseC, unsigned* __restrict__ baseR)
{
    const unsigned* tot = blockIdx.x ? totR : totC;
    unsigned* base = blockIdx.x ? baseR : baseC;
    __shared__ unsigned tsum[256];
    int tid = threadIdx.x;
    unsigned a0 = (2 * tid     < NBK) ? tot[2 * tid]     : 0u;
    unsigned a1 = (2 * tid + 1 < NBK) ? tot[2 * tid + 1] : 0u;
    tsum[tid] = a0 + a1;
    __syncthreads();
    for (int off = 1; off < 256; off <<= 1) {
        unsigned v = (tid >= off) ? tsum[tid - off] : 0u;
        __syncthreads();
        tsum[tid] += v;
        __syncthreads();
    }
    unsigned ex = tid ? tsum[tid - 1] : 0u;
    if (2 * tid     < NBK) base[2 * tid]     = ex;
    if (2 * tid + 1 < NBK) base[2 * tid + 1] = ex + a0;
}

// ---- K4: partition messages into bucket-sorted split streams. Long runs
//      (~33 records = 261B msgS / 66B locS) keep L2 write-back amplification low.
__global__ void __launch_bounds__(256) k_part(
    const int* __restrict__ key,
    const uint2* __restrict__ msgE,
    const unsigned* __restrict__ cm,
    const unsigned* __restrict__ base,
    uint2* __restrict__ msgS,
    unsigned short* __restrict__ locS)
{
    __shared__ uint2 smsg[CHUNK];           // 25.6 KB
    __shared__ unsigned short sloc[CHUNK];  // 6.4 KB
    __shared__ unsigned hist[NBK];
    __shared__ unsigned runstart[NBK + 1];
    __shared__ unsigned gdst[NBK];
    __shared__ unsigned tsum[256];
    int w = blockIdx.x, tid = threadIdx.x, e0 = w * CHUNK;

    if (tid < NBK) {
        hist[tid] = 0u;
        gdst[tid] = base[tid] + cm[(size_t)tid * WGC + w];
    }
    __syncthreads();
    for (int e = e0 + tid; e < e0 + CHUNK; e += 256)
        atomicAdd(&hist[key[e] >> SHIFT], 1u);
    __syncthreads();
    unsigned a0 = (2 * tid     < NBK) ? hist[2 * tid]     : 0u;
    unsigned a1 = (2 * tid + 1 < NBK) ? hist[2 * tid + 1] : 0u;
    tsum[tid] = a0 + a1;
    __syncthreads();
    for (int off = 1; off < 256; off <<= 1) {
        unsigned v = (tid >= off) ? tsum[tid - off] : 0u;
        __syncthreads();
        tsum[tid] += v;
        __syncthreads();
    }
    unsigned ex = tid ? tsum[tid - 1] : 0u;
    if (2 * tid     <= NBK) runstart[2 * tid]     = ex;
    if (2 * tid + 1 <= NBK) runstart[2 * tid + 1] = ex + a0;
    __syncthreads();
    if (tid < NBK) hist[tid] = runstart[tid];   // cursors
    __syncthreads();

    for (int e = e0 + tid; e < e0 + CHUNK; e += 256) {
        int k = key[e];
        int b = k >> SHIFT;
        unsigned pos = atomicAdd(&hist[b], 1u);
        smsg[pos] = msgE[e];
        sloc[pos] = (unsigned short)(k & (NPB - 1));
    }
    __syncthreads();

    // write-out: binary search bucket of slot s (7 steps over 98), long runs
    for (int s = tid; s < CHUNK; s += 256) {
        int lo = 0, hi = NBK;
        while (hi - lo > 1) {
            int mid = (lo + hi) >> 1;
            if (runstart[mid] <= (unsigned)s) lo = mid; else hi = mid;
        }
        size_t g = (size_t)gdst[lo] + (unsigned)s - runstart[lo];
        msgS[g] = smsg[s];
        locS[g] = sloc[s];
    }
}

// ---- K5: PSPLIT WGs per bucket: contiguous stream, f32 LDS acc (16 KB), partials.
__global__ void __launch_bounds__(512) k_reduce(
    const uint2* __restrict__ msgS, const unsigned short* __restrict__ locS,
    const unsigned* __restrict__ base, const unsigned* __restrict__ tot,
    float4* __restrict__ part)          // [PSPLIT][SLOTS]
{
    __shared__ float acc[4][NPB];       // 16 KB
    int b = blockIdx.x / PSPLIT, sub = blockIdx.x % PSPLIT;
    int tid = threadIdx.x;
    for (int i = tid; i < 4 * NPB; i += 512) ((float*)acc)[i] = 0.f;
    __syncthreads();
    unsigned start = base[b], n = tot[b];
    for (unsigned i = start + sub * 512 + tid; i < start + n; i += 512 * PSPLIT) {
        uint2 m = msgS[i];
        int loc = locS[i];
        atomicAdd(&acc[0][loc], __uint_as_float(m.x << 16));
        atomicAdd(&acc[1][loc], __uint_as_float(m.x & 0xffff0000u));
        atomicAdd(&acc[2][loc], __uint_as_float(m.y << 16));
        atomicAdd(&acc[3][loc], __uint_as_float(m.y & 0xffff0000u));
    }
    __syncthreads();
    for (int i = tid; i < NPB; i += 512)
        part[(size_t)sub * SLOTS + (size_t)b * NPB + i] =
            make_float4(acc[0][i], acc[1][i], acc[2][i], acc[3][i]);
}

// ---- K6: merge PSPLIT partial buffers -> final vector
__global__ void __launch_bounds__(256) k_merge(
    const float4* __restrict__ part, float4* __restrict__ vout)
{
    int s = blockIdx.x * 256 + threadIdx.x;
    if (s >= N_NODES) return;
    float4 r = part[s];
    for (int sub = 1; sub < PSPLIT; ++sub) {
        float4 t = part[(size_t)sub * SLOTS + s];
        r.x += t.x; r.y += t.y; r.z += t.z; r.w += t.w;
    }
    vout[s] = r;
}

// ================= fallback path (R3: sector-merged global atomics) =================

__global__ void __launch_bounds__(256) llt_pass1(
    const float* __restrict__ x, const int* __restrict__ row_idx,
    const int* __restrict__ col_idx, const float* __restrict__ boo,
    float* __restrict__ lt)
{
    int t = blockIdx.x * blockDim.x + threadIdx.x;
    if (t >= N_EDGES * 4) return;
    int e = t >> 2, i = t & 3;
    int r = row_idx[e], c = col_idx[e];
    const float* A = boo + (size_t)e * 16;
    const float* xv = x + (size_t)r * 4;
    float m = A[0*4+i]*xv[0] + A[1*4+i]*xv[1] + A[2*4+i]*xv[2] + A[3*4+i]*xv[3];
    atomicAdd(lt + (size_t)c * 4 + i, m);
}

__global__ void __launch_bounds__(256) llt_pass2(
    const float4* __restrict__ lt, const int* __restrict__ row_idx,
    const int* __restrict__ col_idx, const float4* __restrict__ boo,
    float* __restrict__ out)
{
    int t = blockIdx.x * blockDim.x + threadIdx.x;
    if (t >= N_EDGES * 4) return;
    int e = t >> 2, i = t & 3;
    int r = row_idx[e], c = col_idx[e];
    float4 arow = boo[(size_t)e * 4 + i];
    float4 lv = lt[c];
    float m = arow.x*lv.x + arow.y*lv.y + arow.z*lv.z + arow.w*lv.w;
    atomicAdd(out + (size_t)r * 4 + i, m);
}

// ================= host =================

extern "C" void kernel_launch(void* const* d_in, const int* in_sizes, int n_in,
                              void* d_out, int out_size, void* d_ws, size_t ws_size,
                              hipStream_t stream) {
    const float4* x = (const float4*)d_in[0];
    const int* edge_index = (const int*)d_in[1];
    const float4* boo = (const float4*)d_in[2];
    const int* row = edge_index;
    const int* col = edge_index + N_EDGES;
    float4* out = (float4*)d_out;

    auto align256 = [](size_t v) { return (v + 255) & ~(size_t)255; };
    const size_t sz_cm   = align256((size_t)NBK * WGC * 4);       // 392 KB each
    const size_t sz_vec  = align256((size_t)NBK * 4);
    const size_t sz_msgE = align256((size_t)N_EDGES * 8);         // 25.6 MB
    const size_t sz_msgS = align256((size_t)N_EDGES * 8);         // 25.6 MB
    const size_t sz_loc  = align256((size_t)N_EDGES * 2);         // 6.4 MB
    const size_t sz_lt   = align256((size_t)N_NODES * 16);        // 1.6 MB
    const size_t sz_part = align256((size_t)PSPLIT * SLOTS * 16); // 12.8 MB
    const size_t need = 2 * sz_cm + 4 * sz_vec + sz_msgE + sz_msgS + sz_loc
                      + sz_lt + sz_part;

    if (ws_size >= need) {
        char* p = (char*)d_ws;
        unsigned* cmC   = (unsigned*)p; p += sz_cm;
        unsigned* cmR   = (unsigned*)p; p += sz_cm;
        unsigned* totC  = (unsigned*)p; p += sz_vec;
        unsigned* totR  = (unsigned*)p; p += sz_vec;
        unsigned* baseC = (unsigned*)p; p += sz_vec;
        unsigned* baseR = (unsigned*)p; p += sz_vec;
        unsigned short* msgH = (unsigned short*)p;   // view of msgE
        uint2*    msgE  = (uint2*)p;    p += sz_msgE;
        uint2*    msgS  = (uint2*)p;    p += sz_msgS;
        unsigned short* locS = (unsigned short*)p; p += sz_loc;
        float4*   lt    = (float4*)p;   p += sz_lt;
        float4*   part  = (float4*)p;   p += sz_part;

        const int mgrid = (N_EDGES * 4 + 255) / 256;

        k_count<<<WGC, 256, 0, stream>>>(row, col, cmC, cmR);
        k_prefix<<<(2 * NBK + 3) / 4, 256, 0, stream>>>(cmC, cmR, totC, totR);
        k_scan<<<2, 256, 0, stream>>>(totC, totR, baseC, baseR);
        // pass 1: msg = A^T x[row], bucket by col -> lt
        k_msg<1><<<mgrid, 256, 0, stream>>>(row, x, boo, msgH);
        k_part<<<WGC, 256, 0, stream>>>(col, msgE, cmC, baseC, msgS, locS);
        k_reduce<<<NBK * PSPLIT, 512, 0, stream>>>(msgS, locS, baseC, totC, part);
        k_merge<<<(N_NODES + 255) / 256, 256, 0, stream>>>(part, lt);
        // pass 2: msg = A lt[col], bucket by row -> out
        k_msg<0><<<mgrid, 256, 0, stream>>>(col, (const float4*)lt, boo, msgH);
        k_part<<<WGC, 256, 0, stream>>>(row, msgE, cmR, baseR, msgS, locS);
        k_reduce<<<NBK * PSPLIT, 512, 0, stream>>>(msgS, locS, baseR, totR, part);
        k_merge<<<(N_NODES + 255) / 256, 256, 0, stream>>>(part, out);
    } else {
        float* ltf = (float*)d_ws;
        hipMemsetAsync(ltf, 0, (size_t)N_NODES * 4 * sizeof(float), stream);
        hipMemsetAsync(out, 0, (size_t)N_NODES * 4 * sizeof(float), stream);
        const int grid = (N_EDGES * 4 + 255) / 256;
        llt_pass1<<<grid, 256, 0, stream>>>((const float*)x, row, col, (const float*)boo, ltf);
        llt_pass2<<<grid, 256, 0, stream>>>((const float4*)ltf, row, col, boo, (float*)out);
    }
}

// Round 13
// 282.149 us; speedup vs baseline: 1.4116x; 1.3135x over previous
//
#include <hip/hip_runtime.h>

// ---------------- problem constants ----------------
static constexpr int N_NODES = 100000;
static constexpr int N_EDGES = 3200000;
static constexpr int NBK    = 26;                 // fat buckets (DRAM-page locality)
static constexpr int NPB    = 3848;               // nodes/bucket; 26*3848=100048
static constexpr int SLOTS  = NBK * NPB;          // 100048 (node-index identity)
static constexpr int WGC    = 1024;               // partition workgroups
static constexpr int CHUNK  = N_EDGES / WGC;      // 3125 edges / WG (exact)
static constexpr int PSPLIT = 20;                 // contiguous spans per bucket

// record: .x = edge id, .y = src | (loc << 17)   (src < 2^17, loc < 3848 < 2^12)

// ---- K1: per-WG histograms for both keys; transposed count matrices [NBK][WGC]
__global__ void __launch_bounds__(256) k_count(
    const int* __restrict__ row, const int* __restrict__ col,
    unsigned* __restrict__ cmC, unsigned* __restrict__ cmR)
{
    __shared__ unsigned hC[NBK], hR[NBK];
    if (threadIdx.x < NBK) { hC[threadIdx.x] = 0u; hR[threadIdx.x] = 0u; }
    __syncthreads();
    int w = blockIdx.x, e0 = w * CHUNK;
    for (int e = e0 + threadIdx.x; e < e0 + CHUNK; e += 256) {
        atomicAdd(&hC[col[e] / NPB], 1u);
        atomicAdd(&hR[row[e] / NPB], 1u);
    }
    __syncthreads();
    if (threadIdx.x < NBK) {
        cmC[(size_t)threadIdx.x * WGC + w] = hC[threadIdx.x];
        cmR[(size_t)threadIdx.x * WGC + w] = hR[threadIdx.x];
    }
}

// ---- K2: exclusive prefix over WGs per bucket (one warp per bucket row)
__global__ void __launch_bounds__(256) k_prefix(
    unsigned* __restrict__ cmC, unsigned* __restrict__ cmR,
    unsigned* __restrict__ totC, unsigned* __restrict__ totR)
{
    int warp = (blockIdx.x * 256 + threadIdx.x) >> 6;
    int lane = threadIdx.x & 63;
    if (warp >= 2 * NBK) return;
    unsigned* cm  = (warp < NBK) ? cmC : cmR;
    unsigned* tot = (warp < NBK) ? totC : totR;
    int b = (warp < NBK) ? warp : warp - NBK;
    unsigned* rowp = cm + (size_t)b * WGC;
    unsigned carry = 0;
    for (int base = 0; base < WGC; base += 64) {
        unsigned v = rowp[base + lane];
        unsigned inc = v;
        for (int off = 1; off < 64; off <<= 1) {
            unsigned t = __shfl_up(inc, off, 64);
            if (lane >= off) inc += t;
        }
        rowp[base + lane] = carry + inc - v;     // exclusive
        carry += __shfl(inc, 63, 64);
    }
    if (lane == 0) tot[b] = carry;
}

// ---- K3: tiny serial scans of 26 bucket totals -> bases (threads 0 and 1)
__global__ void __launch_bounds__(64) k_scan(
    const unsigned* __restrict__ totC, const unsigned* __restrict__ totR,
    unsigned* __restrict__ baseC, unsigned* __restrict__ baseR)
{
    if (threadIdx.x == 0) {
        unsigned s = 0;
        for (int b = 0; b < NBK; ++b) { baseC[b] = s; s += totC[b]; }
    } else if (threadIdx.x == 1) {
        unsigned s = 0;
        for (int b = 0; b < NBK; ++b) { baseR[b] = s; s += totR[b]; }
    }
}

// ---- K4: partition edges into bucket-sorted records, LDS-staged coalesced writes
__global__ void __launch_bounds__(256) k_part(
    const int* __restrict__ key,       // destination index (col p1 / row p2)
    const int* __restrict__ pay,       // source index      (row p1 / col p2)
    const unsigned* __restrict__ cm,   // prefix'd count matrix [NBK][WGC]
    const unsigned* __restrict__ base, // bucket bases [NBK]
    uint2* __restrict__ perm)
{
    __shared__ uint2 stage[CHUNK];          // 25 KB
    __shared__ unsigned hist[NBK];
    __shared__ unsigned runstart[NBK + 1];
    __shared__ unsigned gdst[NBK];
    int w = blockIdx.x, tid = threadIdx.x, e0 = w * CHUNK;

    if (tid < NBK) {
        hist[tid] = 0u;
        gdst[tid] = base[tid] + cm[(size_t)tid * WGC + w];
    }
    __syncthreads();
    for (int e = e0 + tid; e < e0 + CHUNK; e += 256)
        atomicAdd(&hist[key[e] / NPB], 1u);
    __syncthreads();
    if (tid == 0) {                           // 26-entry serial scan (cheap)
        unsigned s = 0;
        for (int b = 0; b < NBK; ++b) { runstart[b] = s; s += hist[b]; }
        runstart[NBK] = s;
    }
    __syncthreads();
    if (tid < NBK) hist[tid] = runstart[tid]; // cursors
    __syncthreads();
    for (int e = e0 + tid; e < e0 + CHUNK; e += 256) {
        int k = key[e], p = pay[e];
        int b = k / NPB;
        int loc = k - b * NPB;
        unsigned pos = atomicAdd(&hist[b], 1u);
        stage[pos] = make_uint2((unsigned)e,
                                (unsigned)p | ((unsigned)loc << 17));
    }
    __syncthreads();
    for (int s = tid; s < CHUNK; s += 256) {
        int lo = 0, hi = NBK;                 // 5-step binary search
        while (hi - lo > 1) {
            int mid = (lo + hi) >> 1;
            if (runstart[mid] <= (unsigned)s) lo = mid; else hi = mid;
        }
        perm[(size_t)gdst[lo] + (unsigned)s - runstart[lo]] = stage[s];
    }
}

// ---- K5: PSPLIT contiguous spans per bucket. Gather boo (ascending ~1.7KB
//      stride -> DRAM page reuse), accumulate exact f32 in 61.5KB LDS, write
//      partials to per-sub buffer.
template<int TRANS>
__global__ void __launch_bounds__(512) k_reduce(
    const uint2* __restrict__ perm,
    const float4* __restrict__ vin,     // x (pass1) or lt (pass2)
    const float4* __restrict__ boo,
    const unsigned* __restrict__ base, const unsigned* __restrict__ tot,
    float4* __restrict__ part)          // [PSPLIT][SLOTS]
{
    __shared__ float acc[4][NPB];       // 61,568 B
    int b = blockIdx.x / PSPLIT, sub = blockIdx.x % PSPLIT;
    int tid = threadIdx.x;
    for (int i = tid; i < 4 * NPB; i += 512) ((float*)acc)[i] = 0.f;
    __syncthreads();
    unsigned start = base[b], n = tot[b];
    unsigned lo = start + (unsigned)(((unsigned long long)n * sub) / PSPLIT);
    unsigned hi = start + (unsigned)(((unsigned long long)n * (sub + 1)) / PSPLIT);
    for (unsigned i = lo + tid; i < hi; i += 512) {
        uint2 rec = perm[i];
        unsigned e   = rec.x;
        unsigned src = rec.y & 0x1FFFFu;
        unsigned loc = rec.y >> 17;
        float4 v  = vin[src];
        float4 a0 = boo[(size_t)e * 4 + 0];
        float4 a1 = boo[(size_t)e * 4 + 1];
        float4 a2 = boo[(size_t)e * 4 + 2];
        float4 a3 = boo[(size_t)e * 4 + 3];
        float m0, m1, m2, m3;
        if (TRANS) {  // A^T v
            m0 = a0.x * v.x + a1.x * v.y + a2.x * v.z + a3.x * v.w;
            m1 = a0.y * v.x + a1.y * v.y + a2.y * v.z + a3.y * v.w;
            m2 = a0.z * v.x + a1.z * v.y + a2.z * v.z + a3.z * v.w;
            m3 = a0.w * v.x + a1.w * v.y + a2.w * v.z + a3.w * v.w;
        } else {      // A v
            m0 = a0.x * v.x + a0.y * v.y + a0.z * v.z + a0.w * v.w;
            m1 = a1.x * v.x + a1.y * v.y + a1.z * v.z + a1.w * v.w;
            m2 = a2.x * v.x + a2.y * v.y + a2.z * v.z + a2.w * v.w;
            m3 = a3.x * v.x + a3.y * v.y + a3.z * v.z + a3.w * v.w;
        }
        atomicAdd(&acc[0][loc], m0);
        atomicAdd(&acc[1][loc], m1);
        atomicAdd(&acc[2][loc], m2);
        atomicAdd(&acc[3][loc], m3);
    }
    __syncthreads();
    float4* dst = part + (size_t)sub * SLOTS + (size_t)b * NPB;
    for (int i = tid; i < NPB; i += 512)
        dst[i] = make_float4(acc[0][i], acc[1][i], acc[2][i], acc[3][i]);
}

// ---- K6: merge PSPLIT partial buffers -> final vector (slot == node index)
__global__ void __launch_bounds__(256) k_merge(
    const float4* __restrict__ part, float4* __restrict__ vout)
{
    int s = blockIdx.x * 256 + threadIdx.x;
    if (s >= N_NODES) return;
    float4 r = part[s];
    for (int sub = 1; sub < PSPLIT; ++sub) {
        float4 t = part[(size_t)sub * SLOTS + s];
        r.x += t.x; r.y += t.y; r.z += t.z; r.w += t.w;
    }
    vout[s] = r;
}

// ================= fallback path (R3: sector-merged global atomics) =================

__global__ void __launch_bounds__(256) llt_pass1(
    const float* __restrict__ x, const int* __restrict__ row_idx,
    const int* __restrict__ col_idx, const float* __restrict__ boo,
    float* __restrict__ lt)
{
    int t = blockIdx.x * blockDim.x + threadIdx.x;
    if (t >= N_EDGES * 4) return;
    int e = t >> 2, i = t & 3;
    int r = row_idx[e], c = col_idx[e];
    const float* A = boo + (size_t)e * 16;
    const float* xv = x + (size_t)r * 4;
    float m = A[0*4+i]*xv[0] + A[1*4+i]*xv[1] + A[2*4+i]*xv[2] + A[3*4+i]*xv[3];
    atomicAdd(lt + (size_t)c * 4 + i, m);
}

__global__ void __launch_bounds__(256) llt_pass2(
    const float4* __restrict__ lt, const int* __restrict__ row_idx,
    const int* __restrict__ col_idx, const float4* __restrict__ boo,
    float* __restrict__ out)
{
    int t = blockIdx.x * blockDim.x + threadIdx.x;
    if (t >= N_EDGES * 4) return;
    int e = t >> 2, i = t & 3;
    int r = row_idx[e], c = col_idx[e];
    float4 arow = boo[(size_t)e * 4 + i];
    float4 lv = lt[c];
    float m = arow.x*lv.x + arow.y*lv.y + arow.z*lv.z + arow.w*lv.w;
    atomicAdd(out + (size_t)r * 4 + i, m);
}

// ================= host =================

extern "C" void kernel_launch(void* const* d_in, const int* in_sizes, int n_in,
                              void* d_out, int out_size, void* d_ws, size_t ws_size,
                              hipStream_t stream) {
    const float4* x = (const float4*)d_in[0];        // [100000,4] f32
    const int* edge_index = (const int*)d_in[1];     // [2, 3200000] int32
    const float4* boo = (const float4*)d_in[2];      // [3200000,4,4] f32
    const int* row = edge_index;                     // edge_index[0]
    const int* col = edge_index + N_EDGES;           // edge_index[1]
    float4* out = (float4*)d_out;

    auto align256 = [](size_t v) { return (v + 255) & ~(size_t)255; };
    const size_t sz_cm   = align256((size_t)NBK * WGC * 4);       // 104 KB each
    const size_t sz_vec  = align256((size_t)NBK * 4);
    const size_t sz_perm = align256((size_t)N_EDGES * 8);         // 25.6 MB (reused)
    const size_t sz_lt   = align256((size_t)N_NODES * 16);        // 1.6 MB
    const size_t sz_part = align256((size_t)PSPLIT * SLOTS * 16); // 32.0 MB (reused)
    const size_t need = 2 * sz_cm + 4 * sz_vec + sz_perm + sz_lt + sz_part;

    if (ws_size >= need) {
        char* p = (char*)d_ws;
        unsigned* cmC   = (unsigned*)p; p += sz_cm;
        unsigned* cmR   = (unsigned*)p; p += sz_cm;
        unsigned* totC  = (unsigned*)p; p += sz_vec;
        unsigned* totR  = (unsigned*)p; p += sz_vec;
        unsigned* baseC = (unsigned*)p; p += sz_vec;
        unsigned* baseR = (unsigned*)p; p += sz_vec;
        uint2*    perm  = (uint2*)p;    p += sz_perm;
        float4*   lt    = (float4*)p;   p += sz_lt;
        float4*   part  = (float4*)p;   p += sz_part;

        k_count<<<WGC, 256, 0, stream>>>(row, col, cmC, cmR);
        k_prefix<<<(2 * NBK * 64 + 255) / 256, 256, 0, stream>>>(cmC, cmR, totC, totR);
        k_scan<<<1, 64, 0, stream>>>(totC, totR, baseC, baseR);
        // pass 1: bucket by col, src = row, msg = A^T x
        k_part<<<WGC, 256, 0, stream>>>(col, row, cmC, baseC, perm);
        k_reduce<1><<<NBK * PSPLIT, 512, 0, stream>>>(perm, x, boo, baseC, totC, part);
        k_merge<<<(N_NODES + 255) / 256, 256, 0, stream>>>(part, lt);
        // pass 2: bucket by row, src = col, msg = A lt
        k_part<<<WGC, 256, 0, stream>>>(row, col, cmR, baseR, perm);
        k_reduce<0><<<NBK * PSPLIT, 512, 0, stream>>>(perm, (const float4*)lt, boo, baseR, totR, part);
        k_merge<<<(N_NODES + 255) / 256, 256, 0, stream>>>(part, out);
    } else {
        // fallback: sector-merged atomics (R3, 328 us)
        float* ltf = (float*)d_ws;
        hipMemsetAsync(ltf, 0, (size_t)N_NODES * 4 * sizeof(float), stream);
        hipMemsetAsync(out, 0, (size_t)N_NODES * 4 * sizeof(float), stream);
        const int grid = (N_EDGES * 4 + 255) / 256;
        llt_pass1<<<grid, 256, 0, stream>>>((const float*)x, row, col, (const float*)boo, ltf);
        llt_pass2<<<grid, 256, 0, stream>>>((const float4*)ltf, row, col, boo, (float*)out);
    }
}